// Round 8
// baseline (914.881 us; speedup 1.0000x reference)
//
#include <hip/hip_runtime.h>
#include <hip/hip_fp8.h>
#include <cstdint>

typedef float f32x4 __attribute__((ext_vector_type(4)));
typedef int i32x8 __attribute__((ext_vector_type(8)));
typedef long long i64;

static constexpr int Mdim = 8192;
static constexpr int Kdim = 4096;
static constexpr int Ndim = 4096;

// ---- 256^2 tile, single-buffered LDS, 2 blocks/CU ----
static constexpr int BM = 256, BN = 256, BK = 128;  // BK in fp8 bytes
static constexpr int NT = Kdim / BK;                // 32 K-tiles
static constexpr int NWG_M = Mdim / BM;             // 32
static constexpr int NWG_N = Ndim / BN;             // 16
static constexpr int NWG = NWG_M * NWG_N;           // 512 (div by 8)

// ---------------------------------------------------------------------------
__device__ __forceinline__ uint8_t f32_to_e4m3(float f) {
  return (uint8_t)__hip_cvt_float_to_fp8(f, __HIP_SATFINITE, __HIP_E4M3);
}

__global__ __launch_bounds__(256) void quant_fp8_kernel(
    const float* __restrict__ in, uint8_t* __restrict__ out, int n_vec16) {
  const int stride = gridDim.x * blockDim.x;
  for (int i = blockIdx.x * blockDim.x + threadIdx.x; i < n_vec16; i += stride) {
    const float4* src = reinterpret_cast<const float4*>(in) + (size_t)i * 4;
    float4 f0 = src[0], f1 = src[1], f2 = src[2], f3 = src[3];
    const float v[16] = {f0.x, f0.y, f0.z, f0.w, f1.x, f1.y, f1.z, f1.w,
                         f2.x, f2.y, f2.z, f2.w, f3.x, f3.y, f3.z, f3.w};
    union alignas(16) {
      uint32_t u[4];
      uint8_t b[16];
    } r;
#pragma unroll
    for (int j = 0; j < 16; ++j) r.b[j] = f32_to_e4m3(v[j]);
    reinterpret_cast<uint4*>(out)[i] = *reinterpret_cast<const uint4*>(r.u);
  }
}

__device__ __forceinline__ void gload_lds16(const uint8_t* g, uint8_t* l) {
  __builtin_amdgcn_global_load_lds(
      (const __attribute__((address_space(1))) void*)g,
      (__attribute__((address_space(3))) void*)l, 16, 0, 0);
}

__device__ __forceinline__ f32x4 mx_mfma(i32x8 a, i32x8 b, f32x4 c) {
  // fp8 e4m3 A/B, unit e8m0 scales (0x7f) -> identical to non-scaled fp8.
  return __builtin_amdgcn_mfma_scale_f32_16x16x128_f8f6f4(
      a, b, c, 0, 0, 0, 0x7f7f7f7f, 0, 0x7f7f7f7f);
}

// ---------------------------------------------------------------------------
// Round 8: per-CU pipe accounting shows tile time = LDS-pipe (3584cy) +
// MFMA (2210cy) IN SERIES for every intra-block schedule tried (r3-r7 all
// ~6400cy/tile): with 128KiB LDS there is 1 block/CU and all 8 barrier-
// locked waves hit the same phase together. Fix: SINGLE-buffered 64KiB LDS
// -> 2 independent blocks per CU. Block A's MFMA overlaps block B's
// stage/ds_read phases (m114: cross-wave pipe overlap is real). The
// intra-block schedule is intentionally simple:
//   stage(kt) -> vmcnt(0) -> BAR -> compute(kt) -> BAR
// (the drain + HBM latency are hidden by the sibling block, not by
// intra-block pipelining -- which rounds 3-7 proved worthless here).
// setprio(1) around MFMA arbitrates cross-block (real role-split now).
// LDS 16B-chunk XOR swizzle (round-2-verified): linear gload dest,
// pre-swizzled global source, XOR'd ds_read offsets.
// ---------------------------------------------------------------------------
__global__ __launch_bounds__(512, 4) void gemm_fp8_mx_256s(
    const uint8_t* __restrict__ Aq, const uint8_t* __restrict__ Bq,
    const float* __restrict__ bias, const float* __restrict__ sa,
    const float* __restrict__ sb, float* __restrict__ C) {
  __shared__ alignas(16) uint8_t sA[BM * BK];  // 32 KiB
  __shared__ alignas(16) uint8_t sB[BN * BK];  // 32 KiB  (64 KiB total)

  int wg = (int)blockIdx.x;
  wg = (wg & 7) * (NWG / 8) + (wg >> 3);  // XCD swizzle (512 % 8 == 0)
  const int bm0 = (wg / NWG_N) * BM;
  const int bn0 = (wg % NWG_N) * BN;

  const int t = (int)threadIdx.x;  // 0..511
  const int lane = t & 63;
  const int wave = t >> 6;
  const int wm = wave >> 2;  // 0..1
  const int wn = wave & 3;   // 0..3

  // Staging: full tile = 4 calls x (512 thr x 16 B) per matrix.
  // call i: row = i*64 + (t>>3); source chunk pre-swizzled.
  const int srow = t >> 3;
  const int sc16 = (t & 7) ^ (srow & 7);
  const uint8_t* aBase = Aq + (size_t)(bm0 + srow) * Kdim + sc16 * 16;
  const uint8_t* bBase = Bq + (size_t)(bn0 + srow) * Kdim + sc16 * 16;
  const int ldsOff = t * 16;

  // Fragment reads (round-2-verified swizzle)
  const int r7 = lane & 7;
  const int kg = (lane >> 4) * 2;
  const int off0 = (kg ^ r7) * 16;
  const int off1 = ((kg + 1) ^ r7) * 16;
  const int rbA = (wm * 128 + (lane & 15)) * BK;
  const int rbB = (wn * 64 + (lane & 15)) * BK;

  auto ldfrag = [&](const uint8_t* base) -> i32x8 {
    union {
      i32x8 v;
      int4 h[2];
    } u;
    u.h[0] = *reinterpret_cast<const int4*>(base + off0);
    u.h[1] = *reinterpret_cast<const int4*>(base + off1);
    return u.v;
  };

  f32x4 acc[8][4] = {};

#pragma unroll 1
  for (int kt = 0; kt < NT; ++kt) {
    const size_t kb = (size_t)kt * BK;
    // ---- stage tile kt (single buffer; prior BAR guarantees reads done)
#pragma unroll
    for (int i = 0; i < 4; ++i)
      gload_lds16(aBase + kb + (size_t)(i * 64) * Kdim, &sA[i * 8192 + ldsOff]);
#pragma unroll
    for (int i = 0; i < 4; ++i)
      gload_lds16(bBase + kb + (size_t)(i * 64) * Kdim, &sB[i * 8192 + ldsOff]);
    asm volatile("s_waitcnt vmcnt(0)" ::: "memory");
    __builtin_amdgcn_s_barrier();

    // ---- compute tile kt
    i32x8 bf0 = ldfrag(sB + rbB + 0 * 16 * BK);
    i32x8 bf1 = ldfrag(sB + rbB + 1 * 16 * BK);
    i32x8 bf2 = ldfrag(sB + rbB + 2 * 16 * BK);
    i32x8 bf3 = ldfrag(sB + rbB + 3 * 16 * BK);
    i32x8 a0 = ldfrag(sA + rbA + 0 * 16 * BK);
    i32x8 a1 = ldfrag(sA + rbA + 1 * 16 * BK);
    i32x8 a2 = ldfrag(sA + rbA + 2 * 16 * BK);
    i32x8 a3 = ldfrag(sA + rbA + 3 * 16 * BK);

    __builtin_amdgcn_s_setprio(1);
    acc[0][0] = mx_mfma(a0, bf0, acc[0][0]);
    acc[0][1] = mx_mfma(a0, bf1, acc[0][1]);
    acc[0][2] = mx_mfma(a0, bf2, acc[0][2]);
    acc[0][3] = mx_mfma(a0, bf3, acc[0][3]);
    acc[1][0] = mx_mfma(a1, bf0, acc[1][0]);
    acc[1][1] = mx_mfma(a1, bf1, acc[1][1]);
    acc[1][2] = mx_mfma(a1, bf2, acc[1][2]);
    acc[1][3] = mx_mfma(a1, bf3, acc[1][3]);
    __builtin_amdgcn_s_setprio(0);

    i32x8 a4 = ldfrag(sA + rbA + 4 * 16 * BK);
    i32x8 a5 = ldfrag(sA + rbA + 5 * 16 * BK);

    __builtin_amdgcn_s_setprio(1);
    acc[2][0] = mx_mfma(a2, bf0, acc[2][0]);
    acc[2][1] = mx_mfma(a2, bf1, acc[2][1]);
    acc[2][2] = mx_mfma(a2, bf2, acc[2][2]);
    acc[2][3] = mx_mfma(a2, bf3, acc[2][3]);
    acc[3][0] = mx_mfma(a3, bf0, acc[3][0]);
    acc[3][1] = mx_mfma(a3, bf1, acc[3][1]);
    acc[3][2] = mx_mfma(a3, bf2, acc[3][2]);
    acc[3][3] = mx_mfma(a3, bf3, acc[3][3]);
    __builtin_amdgcn_s_setprio(0);

    i32x8 a6 = ldfrag(sA + rbA + 6 * 16 * BK);
    i32x8 a7 = ldfrag(sA + rbA + 7 * 16 * BK);

    __builtin_amdgcn_s_setprio(1);
    acc[4][0] = mx_mfma(a4, bf0, acc[4][0]);
    acc[4][1] = mx_mfma(a4, bf1, acc[4][1]);
    acc[4][2] = mx_mfma(a4, bf2, acc[4][2]);
    acc[4][3] = mx_mfma(a4, bf3, acc[4][3]);
    acc[5][0] = mx_mfma(a5, bf0, acc[5][0]);
    acc[5][1] = mx_mfma(a5, bf1, acc[5][1]);
    acc[5][2] = mx_mfma(a5, bf2, acc[5][2]);
    acc[5][3] = mx_mfma(a5, bf3, acc[5][3]);
    __builtin_amdgcn_s_setprio(0);

    __builtin_amdgcn_s_setprio(1);
    acc[6][0] = mx_mfma(a6, bf0, acc[6][0]);
    acc[6][1] = mx_mfma(a6, bf1, acc[6][1]);
    acc[6][2] = mx_mfma(a6, bf2, acc[6][2]);
    acc[6][3] = mx_mfma(a6, bf3, acc[6][3]);
    acc[7][0] = mx_mfma(a7, bf0, acc[7][0]);
    acc[7][1] = mx_mfma(a7, bf1, acc[7][1]);
    acc[7][2] = mx_mfma(a7, bf2, acc[7][2]);
    acc[7][3] = mx_mfma(a7, bf3, acc[7][3]);
    __builtin_amdgcn_s_setprio(0);

    // all my ds_reads complete (hw lgkm waits precede the MFMAs above);
    // barrier -> every wave done reading -> next stage may overwrite.
    __builtin_amdgcn_s_barrier();
  }

  // ---- epilogue (C/D: col = lane&15, row = (lane>>4)*4 + reg)
  const float scale = sa[0] * sb[0];
  const int orow0 = bm0 + wm * 128 + ((lane >> 4) << 2);
  const int ocol0 = bn0 + wn * 64 + (lane & 15);
#pragma unroll
  for (int n = 0; n < 4; ++n) {
    const int col = ocol0 + n * 16;
    const float bv = bias[col];
#pragma unroll
    for (int m = 0; m < 8; ++m) {
      const int row = orow0 + m * 16;
#pragma unroll
      for (int r = 0; r < 4; ++r)
        C[(size_t)(row + r) * Ndim + col] = acc[m][n][r] * scale + bv;
    }
  }
}

// ---------------------------------------------------------------------------
// Fallback (tiny d_ws only): round-1 fused kernel, known-correct.
// ---------------------------------------------------------------------------
__device__ __forceinline__ void stage16_cvt(const float* g, uint8_t* l) {
  const float4* s = reinterpret_cast<const float4*>(g);
  float4 f0 = s[0], f1 = s[1], f2 = s[2], f3 = s[3];
  const float v[16] = {f0.x, f0.y, f0.z, f0.w, f1.x, f1.y, f1.z, f1.w,
                       f2.x, f2.y, f2.z, f2.w, f3.x, f3.y, f3.z, f3.w};
  union alignas(16) {
    uint32_t u[4];
    uint8_t b[16];
  } r;
#pragma unroll
  for (int j = 0; j < 16; ++j) r.b[j] = f32_to_e4m3(v[j]);
  *reinterpret_cast<uint4*>(l) = *reinterpret_cast<const uint4*>(r.u);
}

__global__ __launch_bounds__(256) void gemm_fp8_fused_kernel(
    const float* __restrict__ X, const float* __restrict__ W,
    const float* __restrict__ bias, const float* __restrict__ sa,
    const float* __restrict__ sb, float* __restrict__ C) {
  constexpr int FBM = 128, FBN = 128, FBK = 64;
  constexpr int FNWG_N = Ndim / FBN;
  __shared__ alignas(16) uint8_t As[FBM * FBK];
  __shared__ alignas(16) uint8_t Bs[FBN * FBK];

  int wg = (int)blockIdx.x;
  const int nwg = (Mdim / FBM) * FNWG_N;
  wg = (wg & 7) * (nwg / 8) + (wg >> 3);
  const int bm0 = (wg / FNWG_N) * FBM;
  const int bn0 = (wg % FNWG_N) * FBN;

  const int t = (int)threadIdx.x;
  const int lane = t & 63;
  const int wave = t >> 6;
  const int wm = wave >> 1, wn = wave & 1;

  const int c0 = t, c1 = t + 256;
  const int r0 = c0 >> 2, col0 = (c0 & 3) * 16;
  const int r1 = c1 >> 2, col1 = (c1 & 3) * 16;
  const float* xa0 = X + (size_t)(bm0 + r0) * Kdim + col0;
  const float* xa1 = X + (size_t)(bm0 + r1) * Kdim + col1;
  const float* wb0 = W + (size_t)(bn0 + r0) * Kdim + col0;
  const float* wb1 = W + (size_t)(bn0 + r1) * Kdim + col1;

  const int arow = (wm * 64 + (lane & 15)) * FBK;
  const int brow = (wn * 64 + (lane & 15)) * FBK;
  const int koff = (lane >> 4) * 8;

  f32x4 acc[4][4] = {};

  for (int kt = 0; kt < Kdim / FBK; ++kt) {
    const int kb = kt * FBK;
    stage16_cvt(xa0 + kb, As + c0 * 16);
    stage16_cvt(xa1 + kb, As + c1 * 16);
    stage16_cvt(wb0 + kb, Bs + c0 * 16);
    stage16_cvt(wb1 + kb, Bs + c1 * 16);
    __syncthreads();
#pragma unroll
    for (int kk = 0; kk < FBK / 32; ++kk) {
      i64 a[4], b[4];
#pragma unroll
      for (int m = 0; m < 4; ++m)
        a[m] = *reinterpret_cast<const i64*>(&As[arow + m * 16 * FBK + kk * 32 + koff]);
#pragma unroll
      for (int n = 0; n < 4; ++n)
        b[n] = *reinterpret_cast<const i64*>(&Bs[brow + n * 16 * FBK + kk * 32 + koff]);
#pragma unroll
      for (int m = 0; m < 4; ++m)
#pragma unroll
        for (int n = 0; n < 4; ++n)
          acc[m][n] = __builtin_amdgcn_mfma_f32_16x16x32_fp8_fp8(
              a[m], b[n], acc[m][n], 0, 0, 0);
    }
    __syncthreads();
  }

  const float scale = sa[0] * sb[0];
  const int orow0 = bm0 + wm * 64 + ((lane >> 4) << 2);
  const int ocol0 = bn0 + wn * 64 + (lane & 15);
#pragma unroll
  for (int n = 0; n < 4; ++n) {
    const int col = ocol0 + n * 16;
    const float bv = bias[col];
#pragma unroll
    for (int m = 0; m < 4; ++m) {
      const int row = orow0 + m * 16;
#pragma unroll
      for (int r = 0; r < 4; ++r)
        C[(size_t)(row + r) * Ndim + col] = acc[m][n][r] * scale + bv;
    }
  }
}

// ---------------------------------------------------------------------------
extern "C" void kernel_launch(void* const* d_in, const int* in_sizes, int n_in,
                              void* d_out, int out_size, void* d_ws, size_t ws_size,
                              hipStream_t stream) {
  const float* x = (const float*)d_in[0];      // [M, K]
  const float* w = (const float*)d_in[1];      // [N, K]
  const float* bias = (const float*)d_in[2];   // [N]
  const float* s_in = (const float*)d_in[3];   // scalar
  const float* s_w = (const float*)d_in[4];    // scalar
  float* out = (float*)d_out;                  // [M, N] fp32

  const size_t needA = (size_t)Mdim * Kdim;  // 32 MiB
  const size_t needB = (size_t)Ndim * Kdim;  // 16 MiB

  if (ws_size >= needA + needB) {
    uint8_t* Aq = (uint8_t*)d_ws;
    uint8_t* Bq = Aq + needA;
    quant_fp8_kernel<<<2048, 256, 0, stream>>>(x, Aq, (int)(needA / 16));
    quant_fp8_kernel<<<2048, 256, 0, stream>>>(w, Bq, (int)(needB / 16));
    gemm_fp8_mx_256s<<<NWG, 512, 0, stream>>>(Aq, Bq, bias, s_in, s_w, out);
  } else {
    gemm_fp8_fused_kernel<<<(Mdim / 128) * (Ndim / 128), 256, 0, stream>>>(
        x, w, bias, s_in, s_w, out);
  }
}

// Round 9
// 271.944 us; speedup vs baseline: 3.3642x; 3.3642x over previous
//
#include <hip/hip_runtime.h>
#include <hip/hip_fp8.h>
#include <cstdint>

typedef float f32x4 __attribute__((ext_vector_type(4)));
typedef int i32x8 __attribute__((ext_vector_type(8)));
typedef long long i64;

static constexpr int Mdim = 8192;
static constexpr int Kdim = 4096;
static constexpr int Ndim = 4096;

// ---- 256^2 tile, A-only LDS (dbuf), B direct from L2 ----
static constexpr int BM = 256, BN = 256, BK = 128;  // BK in fp8 bytes
static constexpr int NT = Kdim / BK;                // 32 K-tiles
static constexpr int NWG_M = Mdim / BM;             // 32
static constexpr int NWG_N = Ndim / BN;             // 16
static constexpr int NWG = NWG_M * NWG_N;           // 512

// ---------------------------------------------------------------------------
__device__ __forceinline__ uint8_t f32_to_e4m3(float f) {
  return (uint8_t)__hip_cvt_float_to_fp8(f, __HIP_SATFINITE, __HIP_E4M3);
}

__global__ __launch_bounds__(256) void quant_fp8_kernel(
    const float* __restrict__ in, uint8_t* __restrict__ out, int n_vec16) {
  const int stride = gridDim.x * blockDim.x;
  for (int i = blockIdx.x * blockDim.x + threadIdx.x; i < n_vec16; i += stride) {
    const float4* src = reinterpret_cast<const float4*>(in) + (size_t)i * 4;
    float4 f0 = src[0], f1 = src[1], f2 = src[2], f3 = src[3];
    const float v[16] = {f0.x, f0.y, f0.z, f0.w, f1.x, f1.y, f1.z, f1.w,
                         f2.x, f2.y, f2.z, f2.w, f3.x, f3.y, f3.z, f3.w};
    union alignas(16) {
      uint32_t u[4];
      uint8_t b[16];
    } r;
#pragma unroll
    for (int j = 0; j < 16; ++j) r.b[j] = f32_to_e4m3(v[j]);
    reinterpret_cast<uint4*>(out)[i] = *reinterpret_cast<const uint4*>(r.u);
  }
}

__device__ __forceinline__ void gload_lds16(const uint8_t* g, uint8_t* l) {
  __builtin_amdgcn_global_load_lds(
      (const __attribute__((address_space(1))) void*)g,
      (__attribute__((address_space(3))) void*)l, 16, 0, 0);
}

__device__ __forceinline__ f32x4 mx_mfma(i32x8 a, i32x8 b, f32x4 c) {
  // fp8 e4m3 A/B, unit e8m0 scales (0x7f) -> identical to non-scaled fp8.
  return __builtin_amdgcn_mfma_scale_f32_16x16x128_f8f6f4(
      a, b, c, 0, 0, 0, 0x7f7f7f7f, 0, 0x7f7f7f7f);
}

// ---------------------------------------------------------------------------
// Round 9: A-only LDS. Rounds 3-7 pinned tile time at LDS-pipe(3580cy) +
// MFMA(2210cy) in series; round 8 proved 2 blocks/CU is register-impossible
// (unified acc+frags ~250 regs/wave, pool 2048/SIMD... -> 8 waves/CU max).
// Lever: B-fragments are register-resident either way (32 VGPR), so source
// them DIRECTLY from global/L2 (2x global_load_dwordx4 per frag, logical
// bytes identical to the LDS path). LDS pipe drops to A-only (~1790cy) <
// MFMA (2210cy). One barrier per tile; waves drift within a tile so wave0's
// MFMA overlaps wave1's ds_reads on each SIMD.
//
// B locality: XCD k owns bn in {2k, 2k+1} (2 x 1MB B-panels -> L2-resident
// per XCD; L3 holds all of A+B=48MB). Mapping is bijective:
//   xcd = wg&7, within = wg>>3, bn = xcd*2 + (within>>5), bm = within&31.
//
// Sync: stage A(kt+1) -> buf[c^1] at tile top (readers of c^1 finished at
// BAR(kt-1)); vmcnt(0) + BAR at tile end => A(kt+1) landed+visible (RAW),
// all reads of buf[c] done (hw lgkm wait precedes last MFMA) (WAR).
// LDS 16B-chunk XOR swizzle on A (round-2-verified).
// ---------------------------------------------------------------------------
__global__ __launch_bounds__(512, 2) void gemm_fp8_mx_bl2(
    const uint8_t* __restrict__ Aq, const uint8_t* __restrict__ Bq,
    const float* __restrict__ bias, const float* __restrict__ sa,
    const float* __restrict__ sb, float* __restrict__ C) {
  __shared__ alignas(16) uint8_t sA[2][BM * BK];  // 2 x 32 KiB (A only)

  const int wg = (int)blockIdx.x;
  const int xcd = wg & 7;
  const int within = wg >> 3;              // 0..63
  const int bn0 = (xcd * 2 + (within >> 5)) * BN;
  const int bm0 = (within & 31) * BM;

  const int t = (int)threadIdx.x;  // 0..511
  const int lane = t & 63;
  const int wave = t >> 6;
  const int wm = wave >> 2;  // 0..1
  const int wn = wave & 3;   // 0..3

  // ---- A staging: full tile = 4 calls x (512 thr x 16 B).
  const int srow = t >> 3;
  const int sc16 = (t & 7) ^ (srow & 7);  // pre-swizzled source chunk
  const uint8_t* aBase = Aq + (size_t)(bm0 + srow) * Kdim + sc16 * 16;
  const int ldsOff = t * 16;

  auto stageA = [&](int buf, int kt) {
    const size_t kb = (size_t)kt * BK;
#pragma unroll
    for (int i = 0; i < 4; ++i)
      gload_lds16(aBase + kb + (size_t)(i * 64) * Kdim,
                  &sA[buf][i * 8192 + ldsOff]);
  };

  // ---- A fragment reads from LDS (round-2-verified swizzle)
  const int r7 = lane & 7;
  const int kg = (lane >> 4) * 2;
  const int off0 = (kg ^ r7) * 16;
  const int off1 = ((kg + 1) ^ r7) * 16;
  const int rbA = (wm * 128 + (lane & 15)) * BK;

  auto ldfrag = [&](const uint8_t* base) -> i32x8 {
    union {
      i32x8 v;
      int4 h[2];
    } u;
    u.h[0] = *reinterpret_cast<const int4*>(base + off0);
    u.h[1] = *reinterpret_cast<const int4*>(base + off1);
    return u.v;
  };

  // ---- B fragments direct from global (L2). Logical bytes identical to
  // the old LDS path: row = bn0 + wn*64 + n*16 + (lane&15),
  // k bytes = kt*128 + (lane>>4)*32, two contiguous 16B halves.
  const uint8_t* bFrag =
      Bq + (size_t)(bn0 + wn * 64 + (lane & 15)) * Kdim + ((lane >> 4) * 32);
  auto ldb = [&](int n, size_t kb) -> i32x8 {
    const uint8_t* p = bFrag + (size_t)(n * 16) * Kdim + kb;
    union {
      i32x8 v;
      int4 h[2];
    } u;
    u.h[0] = *reinterpret_cast<const int4*>(p);
    u.h[1] = *reinterpret_cast<const int4*>(p + 16);
    return u.v;
  };

  f32x4 acc[8][4] = {};

  // ---- prologue
  stageA(0, 0);
  asm volatile("s_waitcnt vmcnt(0)" ::: "memory");
  __builtin_amdgcn_s_barrier();

#pragma unroll 1
  for (int kt = 0; kt < NT; ++kt) {
    const int c = kt & 1;
    const uint8_t* A = &sA[c][0];
    const size_t kb = (size_t)kt * BK;

    // B frags (8 vmem, L2-served) issued first; consumed at chunk0 via the
    // compiler's counted vmcnt (stageA's 4 loads may stay in flight).
    i32x8 bf0 = ldb(0, kb);
    i32x8 bf1 = ldb(1, kb);
    i32x8 bf2 = ldb(2, kb);
    i32x8 bf3 = ldb(3, kb);

    // stage A(kt+1) into the opposite buffer (readers done at BAR(kt-1))
    if (kt + 1 < NT) stageA(c ^ 1, kt + 1);

    // A frags group 0+1
    i32x8 a0 = ldfrag(A + rbA + 0 * 16 * BK);
    i32x8 a1 = ldfrag(A + rbA + 1 * 16 * BK);
    i32x8 a2 = ldfrag(A + rbA + 2 * 16 * BK);
    i32x8 a3 = ldfrag(A + rbA + 3 * 16 * BK);

    __builtin_amdgcn_s_setprio(1);
    acc[0][0] = mx_mfma(a0, bf0, acc[0][0]);
    acc[0][1] = mx_mfma(a0, bf1, acc[0][1]);
    acc[0][2] = mx_mfma(a0, bf2, acc[0][2]);
    acc[0][3] = mx_mfma(a0, bf3, acc[0][3]);
    acc[1][0] = mx_mfma(a1, bf0, acc[1][0]);
    acc[1][1] = mx_mfma(a1, bf1, acc[1][1]);
    acc[1][2] = mx_mfma(a1, bf2, acc[1][2]);
    acc[1][3] = mx_mfma(a1, bf3, acc[1][3]);
    __builtin_amdgcn_s_setprio(0);

    i32x8 a4 = ldfrag(A + rbA + 4 * 16 * BK);
    i32x8 a5 = ldfrag(A + rbA + 5 * 16 * BK);

    __builtin_amdgcn_s_setprio(1);
    acc[2][0] = mx_mfma(a2, bf0, acc[2][0]);
    acc[2][1] = mx_mfma(a2, bf1, acc[2][1]);
    acc[2][2] = mx_mfma(a2, bf2, acc[2][2]);
    acc[2][3] = mx_mfma(a2, bf3, acc[2][3]);
    acc[3][0] = mx_mfma(a3, bf0, acc[3][0]);
    acc[3][1] = mx_mfma(a3, bf1, acc[3][1]);
    acc[3][2] = mx_mfma(a3, bf2, acc[3][2]);
    acc[3][3] = mx_mfma(a3, bf3, acc[3][3]);
    __builtin_amdgcn_s_setprio(0);

    i32x8 a6 = ldfrag(A + rbA + 6 * 16 * BK);
    i32x8 a7 = ldfrag(A + rbA + 7 * 16 * BK);

    __builtin_amdgcn_s_setprio(1);
    acc[4][0] = mx_mfma(a4, bf0, acc[4][0]);
    acc[4][1] = mx_mfma(a4, bf1, acc[4][1]);
    acc[4][2] = mx_mfma(a4, bf2, acc[4][2]);
    acc[4][3] = mx_mfma(a4, bf3, acc[4][3]);
    acc[5][0] = mx_mfma(a5, bf0, acc[5][0]);
    acc[5][1] = mx_mfma(a5, bf1, acc[5][1]);
    acc[5][2] = mx_mfma(a5, bf2, acc[5][2]);
    acc[5][3] = mx_mfma(a5, bf3, acc[5][3]);
    __builtin_amdgcn_s_setprio(0);

    __builtin_amdgcn_s_setprio(1);
    acc[6][0] = mx_mfma(a6, bf0, acc[6][0]);
    acc[6][1] = mx_mfma(a6, bf1, acc[6][1]);
    acc[6][2] = mx_mfma(a6, bf2, acc[6][2]);
    acc[6][3] = mx_mfma(a6, bf3, acc[6][3]);
    acc[7][0] = mx_mfma(a7, bf0, acc[7][0]);
    acc[7][1] = mx_mfma(a7, bf1, acc[7][1]);
    acc[7][2] = mx_mfma(a7, bf2, acc[7][2]);
    acc[7][3] = mx_mfma(a7, bf3, acc[7][3]);
    __builtin_amdgcn_s_setprio(0);

    // single end-of-tile barrier: A(kt+1) landed (vmcnt 0; issued ~2000cy
    // ago) + all waves' reads of buf[c] complete (lgkm waits precede the
    // MFMAs above) -> swap is safe.
    asm volatile("s_waitcnt vmcnt(0)" ::: "memory");
    __builtin_amdgcn_s_barrier();
  }

  // ---- epilogue (C/D: col = lane&15, row = (lane>>4)*4 + reg)
  const float scale = sa[0] * sb[0];
  const int orow0 = bm0 + wm * 128 + ((lane >> 4) << 2);
  const int ocol0 = bn0 + wn * 64 + (lane & 15);
#pragma unroll
  for (int n = 0; n < 4; ++n) {
    const int col = ocol0 + n * 16;
    const float bv = bias[col];
#pragma unroll
    for (int m = 0; m < 8; ++m) {
      const int row = orow0 + m * 16;
#pragma unroll
      for (int r = 0; r < 4; ++r)
        C[(size_t)(row + r) * Ndim + col] = acc[m][n][r] * scale + bv;
    }
  }
}

// ---------------------------------------------------------------------------
// Fallback (tiny d_ws only): round-1 fused kernel, known-correct.
// ---------------------------------------------------------------------------
__device__ __forceinline__ void stage16_cvt(const float* g, uint8_t* l) {
  const float4* s = reinterpret_cast<const float4*>(g);
  float4 f0 = s[0], f1 = s[1], f2 = s[2], f3 = s[3];
  const float v[16] = {f0.x, f0.y, f0.z, f0.w, f1.x, f1.y, f1.z, f1.w,
                       f2.x, f2.y, f2.z, f2.w, f3.x, f3.y, f3.z, f3.w};
  union alignas(16) {
    uint32_t u[4];
    uint8_t b[16];
  } r;
#pragma unroll
  for (int j = 0; j < 16; ++j) r.b[j] = f32_to_e4m3(v[j]);
  *reinterpret_cast<uint4*>(l) = *reinterpret_cast<const uint4*>(r.u);
}

__global__ __launch_bounds__(256) void gemm_fp8_fused_kernel(
    const float* __restrict__ X, const float* __restrict__ W,
    const float* __restrict__ bias, const float* __restrict__ sa,
    const float* __restrict__ sb, float* __restrict__ C) {
  constexpr int FBM = 128, FBN = 128, FBK = 64;
  constexpr int FNWG_N = Ndim / FBN;
  __shared__ alignas(16) uint8_t As[FBM * FBK];
  __shared__ alignas(16) uint8_t Bs[FBN * FBK];

  int wg = (int)blockIdx.x;
  const int nwg = (Mdim / FBM) * FNWG_N;
  wg = (wg & 7) * (nwg / 8) + (wg >> 3);
  const int bm0 = (wg / FNWG_N) * FBM;
  const int bn0 = (wg % FNWG_N) * FBN;

  const int t = (int)threadIdx.x;
  const int lane = t & 63;
  const int wave = t >> 6;
  const int wm = wave >> 1, wn = wave & 1;

  const int c0 = t, c1 = t + 256;
  const int r0 = c0 >> 2, col0 = (c0 & 3) * 16;
  const int r1 = c1 >> 2, col1 = (c1 & 3) * 16;
  const float* xa0 = X + (size_t)(bm0 + r0) * Kdim + col0;
  const float* xa1 = X + (size_t)(bm0 + r1) * Kdim + col1;
  const float* wb0 = W + (size_t)(bn0 + r0) * Kdim + col0;
  const float* wb1 = W + (size_t)(bn0 + r1) * Kdim + col1;

  const int arow = (wm * 64 + (lane & 15)) * FBK;
  const int brow = (wn * 64 + (lane & 15)) * FBK;
  const int koff = (lane >> 4) * 8;

  f32x4 acc[4][4] = {};

  for (int kt = 0; kt < Kdim / FBK; ++kt) {
    const int kb = kt * FBK;
    stage16_cvt(xa0 + kb, As + c0 * 16);
    stage16_cvt(xa1 + kb, As + c1 * 16);
    stage16_cvt(wb0 + kb, Bs + c0 * 16);
    stage16_cvt(wb1 + kb, Bs + c1 * 16);
    __syncthreads();
#pragma unroll
    for (int kk = 0; kk < FBK / 32; ++kk) {
      i64 a[4], b[4];
#pragma unroll
      for (int m = 0; m < 4; ++m)
        a[m] = *reinterpret_cast<const i64*>(&As[arow + m * 16 * FBK + kk * 32 + koff]);
#pragma unroll
      for (int n = 0; n < 4; ++n)
        b[n] = *reinterpret_cast<const i64*>(&Bs[brow + n * 16 * FBK + kk * 32 + koff]);
#pragma unroll
      for (int m = 0; m < 4; ++m)
#pragma unroll
        for (int n = 0; n < 4; ++n)
          acc[m][n] = __builtin_amdgcn_mfma_f32_16x16x32_fp8_fp8(
              a[m], b[n], acc[m][n], 0, 0, 0);
    }
    __syncthreads();
  }

  const float scale = sa[0] * sb[0];
  const int orow0 = bm0 + wm * 64 + ((lane >> 4) << 2);
  const int ocol0 = bn0 + wn * 64 + (lane & 15);
#pragma unroll
  for (int n = 0; n < 4; ++n) {
    const int col = ocol0 + n * 16;
    const float bv = bias[col];
#pragma unroll
    for (int m = 0; m < 4; ++m) {
      const int row = orow0 + m * 16;
#pragma unroll
      for (int r = 0; r < 4; ++r)
        C[(size_t)(row + r) * Ndim + col] = acc[m][n][r] * scale + bv;
    }
  }
}

// ---------------------------------------------------------------------------
extern "C" void kernel_launch(void* const* d_in, const int* in_sizes, int n_in,
                              void* d_out, int out_size, void* d_ws, size_t ws_size,
                              hipStream_t stream) {
  const float* x = (const float*)d_in[0];      // [M, K]
  const float* w = (const float*)d_in[1];      // [N, K]
  const float* bias = (const float*)d_in[2];   // [N]
  const float* s_in = (const float*)d_in[3];   // scalar
  const float* s_w = (const float*)d_in[4];    // scalar
  float* out = (float*)d_out;                  // [M, N] fp32

  const size_t needA = (size_t)Mdim * Kdim;  // 32 MiB
  const size_t needB = (size_t)Ndim * Kdim;  // 16 MiB

  if (ws_size >= needA + needB) {
    uint8_t* Aq = (uint8_t*)d_ws;
    uint8_t* Bq = Aq + needA;
    quant_fp8_kernel<<<2048, 256, 0, stream>>>(x, Aq, (int)(needA / 16));
    quant_fp8_kernel<<<2048, 256, 0, stream>>>(w, Bq, (int)(needB / 16));
    gemm_fp8_mx_bl2<<<NWG, 512, 0, stream>>>(Aq, Bq, bias, s_in, s_w, out);
  } else {
    gemm_fp8_fused_kernel<<<(Mdim / 128) * (Ndim / 128), 256, 0, stream>>>(
        x, w, bias, s_in, s_w, out);
  }
}

// Round 10
// 216.176 us; speedup vs baseline: 4.2321x; 1.2580x over previous
//
#include <hip/hip_runtime.h>
#include <hip/hip_fp8.h>
#include <cstdint>

typedef float f32x4 __attribute__((ext_vector_type(4)));
typedef int i32x8 __attribute__((ext_vector_type(8)));
typedef long long i64;

static constexpr int Mdim = 8192;
static constexpr int Kdim = 4096;
static constexpr int Ndim = 4096;

// ---- 256^2 tile, A-only LDS (dbuf), B packed fragment-major from L2 ----
static constexpr int BM = 256, BN = 256, BK = 128;  // BK in fp8 bytes
static constexpr int NT = Kdim / BK;                // 32 K-tiles
static constexpr int NWG_M = Mdim / BM;             // 32
static constexpr int NWG_N = Ndim / BN;             // 16
static constexpr int NWG = NWG_M * NWG_N;           // 512

// Packed-B layout: PB[((rb*32 + kt)*2 + h)*1024 + (kq*16 + r15)*16]
//   rb = global_row/16 (0..255), kt = K-tile (0..31), h = 16B half (0..1),
//   kq = k-quarter = lane>>4, r15 = row%16 = lane&15.
// GEMM reads: p = PB + (rb*32+kt)*2048 + lane*16; halves at p, p+1024 ->
// two perfectly coalesced 1KB wave bursts per fragment.

// ---------------------------------------------------------------------------
__device__ __forceinline__ uint8_t f32_to_e4m3(float f) {
  return (uint8_t)__hip_cvt_float_to_fp8(f, __HIP_SATFINITE, __HIP_E4M3);
}

__device__ __forceinline__ uint4 cvt16(const float4 f0, const float4 f1,
                                       const float4 f2, const float4 f3) {
  const float v[16] = {f0.x, f0.y, f0.z, f0.w, f1.x, f1.y, f1.z, f1.w,
                       f2.x, f2.y, f2.z, f2.w, f3.x, f3.y, f3.z, f3.w};
  union alignas(16) {
    uint32_t u[4];
    uint8_t b[16];
    uint4 q;
  } r;
#pragma unroll
  for (int j = 0; j < 16; ++j) r.b[j] = f32_to_e4m3(v[j]);
  return r.q;
}

__global__ __launch_bounds__(256) void quant_fp8_kernel(
    const float* __restrict__ in, uint8_t* __restrict__ out, int n_vec16) {
  const int stride = gridDim.x * blockDim.x;
  for (int i = blockIdx.x * blockDim.x + threadIdx.x; i < n_vec16; i += stride) {
    const float4* src = reinterpret_cast<const float4*>(in) + (size_t)i * 4;
    reinterpret_cast<uint4*>(out)[i] = cvt16(src[0], src[1], src[2], src[3]);
  }
}

// W quantize + pack into fragment-major PB. t -> (g = t>>8, kbi = t&255):
// reads 16 consecutive f32 of row g (fully coalesced); writes 16B at packed
// offset. kb = kbi*16 = kt*128 + kq*32 + h*16 -> kt=kbi>>3, kq=(kbi>>1)&3,
// h=kbi&1.
__global__ __launch_bounds__(256) void quant_pack_w_kernel(
    const float* __restrict__ W, uint8_t* __restrict__ PB) {
  const int stride = gridDim.x * blockDim.x;
  const int total = (Ndim / 16) * (Kdim / 16) * 16;  // N*K/16 = 1M
  for (int t = blockIdx.x * blockDim.x + threadIdx.x; t < total; t += stride) {
    const int g = t >> 8;
    const int kbi = t & 255;
    const int kt = kbi >> 3;
    const int kq = (kbi >> 1) & 3;
    const int h = kbi & 1;
    const int rb = g >> 4, r15 = g & 15;
    const float4* src =
        reinterpret_cast<const float4*>(W + (size_t)g * Kdim + kbi * 16);
    const size_t o = (((size_t)(rb * 32 + kt) * 2 + h) * 4 + kq) * 16 + r15;
    reinterpret_cast<uint4*>(PB)[o] = cvt16(src[0], src[1], src[2], src[3]);
  }
}

__device__ __forceinline__ void gload_lds16(const uint8_t* g, uint8_t* l) {
  __builtin_amdgcn_global_load_lds(
      (const __attribute__((address_space(1))) void*)g,
      (__attribute__((address_space(3))) void*)l, 16, 0, 0);
}

__device__ __forceinline__ f32x4 mx_mfma(i32x8 a, i32x8 b, f32x4 c) {
  // fp8 e4m3 A/B, unit e8m0 scales (0x7f) -> identical to non-scaled fp8.
  return __builtin_amdgcn_mfma_scale_f32_16x16x128_f8f6f4(
      a, b, c, 0, 0, 0, 0x7f7f7f7f, 0, 0x7f7f7f7f);
}

// ---------------------------------------------------------------------------
// Round 10: A-only LDS + packed-B. LDS pipe/tile drops 3584 -> ~2300 cy
// (128 A ds_reads + A-only writes) < MFMA 2214. B frags arrive as coalesced
// 1KB bursts from L2 (XCD-pinned 2MB panels). One barrier per tile.
// Sync (round-9-verified pattern): stageA(kt+1)->buf[c^1] (readers finished
// at BAR(kt-1)); vmcnt(0)+BAR at tile end (stage landed + all reads done).
// bf loads issued FIRST -> compiler waits them (vmcnt(4)) before chunk0
// while stageA's 4 loads stay in flight.
// ---------------------------------------------------------------------------
__global__ __launch_bounds__(512, 2) void gemm_fp8_mx_pb(
    const uint8_t* __restrict__ Aq, const uint8_t* __restrict__ PB,
    const float* __restrict__ bias, const float* __restrict__ sa,
    const float* __restrict__ sb, float* __restrict__ C) {
  __shared__ alignas(16) uint8_t sA[2][BM * BK];  // 2 x 32 KiB (A only)

  const int wg = (int)blockIdx.x;
  const int xcd = wg & 7;
  const int within = wg >> 3;  // 0..63
  const int bn0 = (xcd * 2 + (within >> 5)) * BN;  // XCD-pinned B panels
  const int bm0 = (within & 31) * BM;

  const int t = (int)threadIdx.x;  // 0..511
  const int lane = t & 63;
  const int wave = t >> 6;
  const int wm = wave >> 2;  // 0..1
  const int wn = wave & 3;   // 0..3

  // ---- A staging (round-2-verified swizzle): 4 calls x 512 thr x 16 B.
  const int srow = t >> 3;
  const int sc16 = (t & 7) ^ (srow & 7);
  const uint8_t* aBase = Aq + (size_t)(bm0 + srow) * Kdim + sc16 * 16;
  const int ldsOff = t * 16;

  auto stageA = [&](int buf, int kt) {
    const size_t kb = (size_t)kt * BK;
#pragma unroll
    for (int i = 0; i < 4; ++i)
      gload_lds16(aBase + kb + (size_t)(i * 64) * Kdim,
                  &sA[buf][i * 8192 + ldsOff]);
  };

  // ---- A fragment reads from LDS
  const int r7 = lane & 7;
  const int kg = (lane >> 4) * 2;
  const int off0 = (kg ^ r7) * 16;
  const int off1 = ((kg + 1) ^ r7) * 16;
  const int rbA = (wm * 128 + (lane & 15)) * BK;

  auto ldfrag = [&](const uint8_t* base) -> i32x8 {
    union {
      i32x8 v;
      int4 h[2];
    } u;
    u.h[0] = *reinterpret_cast<const int4*>(base + off0);
    u.h[1] = *reinterpret_cast<const int4*>(base + off1);
    return u.v;
  };

  // ---- B fragments from packed layout (coalesced: base + lane*16)
  const int rbB0 = (bn0 >> 4) + wn * 4;  // row-block of frag n=0
  auto ldb = [&](int n, int kt) -> i32x8 {
    const uint8_t* p =
        PB + ((size_t)((rbB0 + n) * 32 + kt) * 2048) + lane * 16;
    union {
      i32x8 v;
      int4 h[2];
    } u;
    u.h[0] = *reinterpret_cast<const int4*>(p);
    u.h[1] = *reinterpret_cast<const int4*>(p + 1024);
    return u.v;
  };

  f32x4 acc[8][4] = {};

  // ---- prologue
  stageA(0, 0);
  asm volatile("s_waitcnt vmcnt(0)" ::: "memory");
  __builtin_amdgcn_s_barrier();

#pragma unroll 1
  for (int kt = 0; kt < NT; ++kt) {
    const int c = kt & 1;
    const uint8_t* A = &sA[c][0];

    // B frags first (oldest in vmem queue -> chunk0 waits these, not stage)
    i32x8 bf0 = ldb(0, kt);
    i32x8 bf1 = ldb(1, kt);
    i32x8 bf2 = ldb(2, kt);
    i32x8 bf3 = ldb(3, kt);

    // stage A(kt+1) into the opposite buffer (readers done at BAR(kt-1))
    if (kt + 1 < NT) stageA(c ^ 1, kt + 1);

    i32x8 a0 = ldfrag(A + rbA + 0 * 16 * BK);
    i32x8 a1 = ldfrag(A + rbA + 1 * 16 * BK);
    i32x8 a2 = ldfrag(A + rbA + 2 * 16 * BK);
    i32x8 a3 = ldfrag(A + rbA + 3 * 16 * BK);

    __builtin_amdgcn_s_setprio(1);
    acc[0][0] = mx_mfma(a0, bf0, acc[0][0]);
    acc[0][1] = mx_mfma(a0, bf1, acc[0][1]);
    acc[0][2] = mx_mfma(a0, bf2, acc[0][2]);
    acc[0][3] = mx_mfma(a0, bf3, acc[0][3]);
    acc[1][0] = mx_mfma(a1, bf0, acc[1][0]);
    acc[1][1] = mx_mfma(a1, bf1, acc[1][1]);
    acc[1][2] = mx_mfma(a1, bf2, acc[1][2]);
    acc[1][3] = mx_mfma(a1, bf3, acc[1][3]);
    __builtin_amdgcn_s_setprio(0);

    i32x8 a4 = ldfrag(A + rbA + 4 * 16 * BK);
    i32x8 a5 = ldfrag(A + rbA + 5 * 16 * BK);

    __builtin_amdgcn_s_setprio(1);
    acc[2][0] = mx_mfma(a2, bf0, acc[2][0]);
    acc[2][1] = mx_mfma(a2, bf1, acc[2][1]);
    acc[2][2] = mx_mfma(a2, bf2, acc[2][2]);
    acc[2][3] = mx_mfma(a2, bf3, acc[2][3]);
    acc[3][0] = mx_mfma(a3, bf0, acc[3][0]);
    acc[3][1] = mx_mfma(a3, bf1, acc[3][1]);
    acc[3][2] = mx_mfma(a3, bf2, acc[3][2]);
    acc[3][3] = mx_mfma(a3, bf3, acc[3][3]);
    __builtin_amdgcn_s_setprio(0);

    i32x8 a6 = ldfrag(A + rbA + 6 * 16 * BK);
    i32x8 a7 = ldfrag(A + rbA + 7 * 16 * BK);

    __builtin_amdgcn_s_setprio(1);
    acc[4][0] = mx_mfma(a4, bf0, acc[4][0]);
    acc[4][1] = mx_mfma(a4, bf1, acc[4][1]);
    acc[4][2] = mx_mfma(a4, bf2, acc[4][2]);
    acc[4][3] = mx_mfma(a4, bf3, acc[4][3]);
    acc[5][0] = mx_mfma(a5, bf0, acc[5][0]);
    acc[5][1] = mx_mfma(a5, bf1, acc[5][1]);
    acc[5][2] = mx_mfma(a5, bf2, acc[5][2]);
    acc[5][3] = mx_mfma(a5, bf3, acc[5][3]);
    __builtin_amdgcn_s_setprio(0);

    __builtin_amdgcn_s_setprio(1);
    acc[6][0] = mx_mfma(a6, bf0, acc[6][0]);
    acc[6][1] = mx_mfma(a6, bf1, acc[6][1]);
    acc[6][2] = mx_mfma(a6, bf2, acc[6][2]);
    acc[6][3] = mx_mfma(a6, bf3, acc[6][3]);
    acc[7][0] = mx_mfma(a7, bf0, acc[7][0]);
    acc[7][1] = mx_mfma(a7, bf1, acc[7][1]);
    acc[7][2] = mx_mfma(a7, bf2, acc[7][2]);
    acc[7][3] = mx_mfma(a7, bf3, acc[7][3]);
    __builtin_amdgcn_s_setprio(0);

    // single end-of-tile barrier: stageA(kt+1) landed (vmcnt 0, issued
    // ~2000cy earlier) + all waves' buf[c] reads complete -> swap safe.
    asm volatile("s_waitcnt vmcnt(0)" ::: "memory");
    __builtin_amdgcn_s_barrier();
  }

  // ---- epilogue (C/D: col = lane&15, row = (lane>>4)*4 + reg)
  const float scale = sa[0] * sb[0];
  const int orow0 = bm0 + wm * 128 + ((lane >> 4) << 2);
  const int ocol0 = bn0 + wn * 64 + (lane & 15);
#pragma unroll
  for (int n = 0; n < 4; ++n) {
    const int col = ocol0 + n * 16;
    const float bv = bias[col];
#pragma unroll
    for (int m = 0; m < 8; ++m) {
      const int row = orow0 + m * 16;
#pragma unroll
      for (int r = 0; r < 4; ++r)
        C[(size_t)(row + r) * Ndim + col] = acc[m][n][r] * scale + bv;
    }
  }
}

// ---------------------------------------------------------------------------
// Fallback (tiny d_ws only): round-1 fused kernel, known-correct.
// ---------------------------------------------------------------------------
__device__ __forceinline__ void stage16_cvt(const float* g, uint8_t* l) {
  const float4* s = reinterpret_cast<const float4*>(g);
  uint4 q = cvt16(s[0], s[1], s[2], s[3]);
  *reinterpret_cast<uint4*>(l) = q;
}

__global__ __launch_bounds__(256) void gemm_fp8_fused_kernel(
    const float* __restrict__ X, const float* __restrict__ W,
    const float* __restrict__ bias, const float* __restrict__ sa,
    const float* __restrict__ sb, float* __restrict__ C) {
  constexpr int FBM = 128, FBN = 128, FBK = 64;
  constexpr int FNWG_N = Ndim / FBN;
  __shared__ alignas(16) uint8_t As[FBM * FBK];
  __shared__ alignas(16) uint8_t Bs[FBN * FBK];

  int wg = (int)blockIdx.x;
  const int nwg = (Mdim / FBM) * FNWG_N;
  wg = (wg & 7) * (nwg / 8) + (wg >> 3);
  const int bm0 = (wg / FNWG_N) * FBM;
  const int bn0 = (wg % FNWG_N) * FBN;

  const int t = (int)threadIdx.x;
  const int lane = t & 63;
  const int wave = t >> 6;
  const int wm = wave >> 1, wn = wave & 1;

  const int c0 = t, c1 = t + 256;
  const int r0 = c0 >> 2, col0 = (c0 & 3) * 16;
  const int r1 = c1 >> 2, col1 = (c1 & 3) * 16;
  const float* xa0 = X + (size_t)(bm0 + r0) * Kdim + col0;
  const float* xa1 = X + (size_t)(bm0 + r1) * Kdim + col1;
  const float* wb0 = W + (size_t)(bn0 + r0) * Kdim + col0;
  const float* wb1 = W + (size_t)(bn0 + r1) * Kdim + col1;

  const int arow = (wm * 64 + (lane & 15)) * FBK;
  const int brow = (wn * 64 + (lane & 15)) * FBK;
  const int koff = (lane >> 4) * 8;

  f32x4 acc[4][4] = {};

  for (int kt = 0; kt < Kdim / FBK; ++kt) {
    const int kb = kt * FBK;
    stage16_cvt(xa0 + kb, As + c0 * 16);
    stage16_cvt(xa1 + kb, As + c1 * 16);
    stage16_cvt(wb0 + kb, Bs + c0 * 16);
    stage16_cvt(wb1 + kb, Bs + c1 * 16);
    __syncthreads();
#pragma unroll
    for (int kk = 0; kk < FBK / 32; ++kk) {
      i64 a[4], b[4];
#pragma unroll
      for (int m = 0; m < 4; ++m)
        a[m] = *reinterpret_cast<const i64*>(&As[arow + m * 16 * FBK + kk * 32 + koff]);
#pragma unroll
      for (int n = 0; n < 4; ++n)
        b[n] = *reinterpret_cast<const i64*>(&Bs[brow + n * 16 * FBK + kk * 32 + koff]);
#pragma unroll
      for (int m = 0; m < 4; ++m)
#pragma unroll
        for (int n = 0; n < 4; ++n)
          acc[m][n] = __builtin_amdgcn_mfma_f32_16x16x32_fp8_fp8(
              a[m], b[n], acc[m][n], 0, 0, 0);
    }
    __syncthreads();
  }

  const float scale = sa[0] * sb[0];
  const int orow0 = bm0 + wm * 64 + ((lane >> 4) << 2);
  const int ocol0 = bn0 + wn * 64 + (lane & 15);
#pragma unroll
  for (int n = 0; n < 4; ++n) {
    const int col = ocol0 + n * 16;
    const float bv = bias[col];
#pragma unroll
    for (int m = 0; m < 4; ++m) {
      const int row = orow0 + m * 16;
#pragma unroll
      for (int r = 0; r < 4; ++r)
        C[(size_t)(row + r) * Ndim + col] = acc[m][n][r] * scale + bv;
    }
  }
}

// ---------------------------------------------------------------------------
extern "C" void kernel_launch(void* const* d_in, const int* in_sizes, int n_in,
                              void* d_out, int out_size, void* d_ws, size_t ws_size,
                              hipStream_t stream) {
  const float* x = (const float*)d_in[0];      // [M, K]
  const float* w = (const float*)d_in[1];      // [N, K]
  const float* bias = (const float*)d_in[2];   // [N]
  const float* s_in = (const float*)d_in[3];   // scalar
  const float* s_w = (const float*)d_in[4];    // scalar
  float* out = (float*)d_out;                  // [M, N] fp32

  const size_t needA = (size_t)Mdim * Kdim;  // 32 MiB
  const size_t needB = (size_t)Ndim * Kdim;  // 16 MiB (packed)

  if (ws_size >= needA + needB) {
    uint8_t* Aq = (uint8_t*)d_ws;
    uint8_t* PB = Aq + needA;
    quant_fp8_kernel<<<2048, 256, 0, stream>>>(x, Aq, (int)(needA / 16));
    quant_pack_w_kernel<<<2048, 256, 0, stream>>>(w, PB);
    gemm_fp8_mx_pb<<<NWG, 512, 0, stream>>>(Aq, PB, bias, s_in, s_w, out);
  } else {
    gemm_fp8_fused_kernel<<<(Mdim / 128) * (Ndim / 128), 256, 0, stream>>>(
        x, w, bias, s_in, s_w, out);
  }
}